// Round 11
// baseline (188.202 us; speedup 1.0000x reference)
//
#include <hip/hip_runtime.h>
#include <hip/hip_bf16.h>

typedef __attribute__((ext_vector_type(8))) short short8;
typedef __attribute__((ext_vector_type(4))) float floatx4;
typedef __attribute__((ext_vector_type(4))) int intx4;
typedef __attribute__((ext_vector_type(4))) unsigned int uintx4;

#define NNODES 40000
#define CH 128
#define NCLS 40
#define LDK 136   // 128 + 8 pad (bf16 elems) -> row stride 272 B, 16B-aligned
#define CAP 64    // padded-CSR slots per node (deg ~ Poisson(16); P(deg>64)~0)
#define PBLKS (NNODES / 8)                 // 5000 blocks per gather pass (8 nodes/blk)

#define WT_ELEMS (4 * CH * CH + 48 * CH)   // 71680
#define WT_BLKS  ((WT_ELEMS + 255) / 256)  // 280
#define CVT_N4   (NNODES * CH / 4)         // 1,280,000
#define CVT_BLKS ((CVT_N4 + 255) / 256)    // 5000
#define CNTZ_BLKS ((NNODES + 1023) / 1024) // zero 40000 ints, int4 x 256thr

__device__ __forceinline__ unsigned short f2bf(float f) {
    union { float f; unsigned int u; } a; a.f = f;
    unsigned int r = a.u + 0x7FFFu + ((a.u >> 16) & 1u);
    return (unsigned short)(r >> 16);
}
__device__ __forceinline__ float bflo(unsigned int w) {
    union { unsigned int u; float f; } a; a.u = w << 16; return a.f;
}
__device__ __forceinline__ float bfhi(unsigned int w) {
    union { unsigned int u; float f; } a; a.u = w & 0xffff0000u; return a.f;
}

// R0 structure (proven best): separate prep_all and fill_slots.
__global__ __launch_bounds__(256) void prep_all(
        const float* __restrict__ w1a, const float* __restrict__ w1b,
        const float* __restrict__ w2a, const float* __restrict__ w2b,
        const float* __restrict__ wlin, const float* __restrict__ x,
        unsigned short* __restrict__ wt, unsigned short* __restrict__ xb,
        int* __restrict__ cnt) {
    int b = blockIdx.x;
    if (b < WT_BLKS) {
        int tid = b * 256 + threadIdx.x;
        const int M = CH * CH;
        if (tid < 4 * M) {
            int m = tid / M;
            int n = (tid % M) / CH;   // out channel
            int k = tid % CH;         // in channel
            const float* w = (m == 0) ? w1a : (m == 1) ? w1b : (m == 2) ? w2a : w2b;
            wt[tid] = f2bf(w[k * CH + n]);
        } else if (tid < WT_ELEMS) {
            int t = tid - 4 * M;
            int n = t / CH, k = t % CH;
            wt[tid] = (n < NCLS) ? f2bf(wlin[k * NCLS + n]) : (unsigned short)0;
        }
    } else if (b < WT_BLKS + CVT_BLKS) {
        int t = (b - WT_BLKS) * 256 + threadIdx.x;
        if (t < CVT_N4) {
            floatx4 v = __builtin_nontemporal_load((const floatx4*)(x + (long long)t * 4));
            union { unsigned short us[4]; uint2 u2; } pk;
            pk.us[0] = f2bf(v.x); pk.us[1] = f2bf(v.y);
            pk.us[2] = f2bf(v.z); pk.us[3] = f2bf(v.w);
            *(uint2*)(xb + (long long)t * 4) = pk.u2;
        }
    } else {
        int idx = (b - WT_BLKS - CVT_BLKS) * 1024 + threadIdx.x * 4;
        if (idx < NNODES) *(int4*)(cnt + idx) = make_int4(0, 0, 0, 0);
    }
}

// R17 fill (champion): 1 edge/thread, full-occupancy in-flight atomics.
// Remaining ~40us is the device-scope returning-atomic throughput wall
// (~16 G atomics/s) — R12 (padding) and R17 (TLP) bracket it; stop here.
__global__ __launch_bounds__(256) void fill_slots(const int* __restrict__ srcv,
                                                  const int* __restrict__ dstv,
                                                  int* __restrict__ cnt,
                                                  unsigned short* __restrict__ slots, int E) {
    int t = blockIdx.x * blockDim.x + threadIdx.x;
    if (t >= E) return;
    int s = srcv[t];
    int d = dstv[t];
    int pos = atomicAdd(&cnt[d], 1);
    if (pos < CAP) slots[((long long)d << 6) + pos] = (unsigned short)s;
}

// out[node] = xb[node] + sum_edges xb[src]   (bf16 in, fp32 acc, bf16 out)
// R16 structure + R19: ANTI-POLLUTION pass. Theory: each gather moves
// ~175 MB of random 128-B line reads in ~48us = 3.6 TB/s (L3/fabric rate,
// 10x under L2). R16's half-split (5.12 MB xb) was neutral NOT because
// the gather is cache-insensitive, but because slots (5.12 MB, cached
// loads!), cnt, and the out write-allocate stream shared the same 4 MB
// per-XCD L2 -> xb never became resident. Fix: NT loads for slots/cnt
// (streamed, zero reuse), NT store for out (never re-read this pass;
// mlp refetches 10 MB at ~2us). L2 then holds only the 5.12 MB xb half.
// (R20: NT store must use ext_vector_type, not HIP uint4 — compile fix.)
__global__ __launch_bounds__(256, 8)
void gather_split(const unsigned short* __restrict__ xb,
                  const int* __restrict__ cnt,
                  const unsigned short* __restrict__ slots,
                  unsigned short* __restrict__ out) {
    int bid = blockIdx.x;
    const int pass = (bid >= PBLKS) ? 1 : 0;
    const int nb = bid - pass * PBLKS;
    const int wave = threadIdx.x >> 6;
    const int lane = threadIdx.x & 63;
    const int h = lane >> 5;                 // 0: node A half, 1: node B half
    const int l32 = lane & 31;
    const int g = l32 >> 3;                  // slot quarter 0..3 (i mod 4 partition)
    const int c = (lane & 7) * 8 + pass * 64;// channel base (bf16 elems)
    const int nA = nb * 8 + wave * 2;
    const int nB = nA + 1;
    const int node = h ? nB : nA;
    int degA = __builtin_nontemporal_load(&cnt[nA]); degA = (degA > CAP) ? CAP : degA;
    int degB = __builtin_nontemporal_load(&cnt[nB]); degB = (degB > CAP) ? CAP : degB;
    const int deg = h ? degB : degA;
    const long long selfoff = (long long)node * CH;

    // lanes 0-31 hold A's slots 0..31, lanes 32-63 hold B's slots 0..31
    // NT: slot lines have zero intra-pass reuse — keep them out of L2.
    int e0 = (int)__builtin_nontemporal_load(&slots[((long long)node << 6) + l32]);

    float acc[8];
    #pragma unroll
    for (int k = 0; k < 8; ++k) acc[k] = 0.f;

    if (degA <= 32 && degB <= 32) {          // wave-uniform branch
        // ---- fast path: branchless, 8+1 loads in flight per lane ----
        uint4 u[8];
        int iv[8];
        #pragma unroll
        for (int k = 0; k < 8; ++k) {
            int i = k * 4 + g;               // 0..31
            int s = __shfl(e0, i + h * 32);  // full-exec shfl, own half
            iv[k] = i;
            long long off = (i < deg) ? (long long)s * CH : selfoff;
            u[k] = *(const uint4*)(xb + off + c);
        }
        uint4 uself = *(const uint4*)(xb + selfoff + c);
        if (g == 0) {   // self term (eps = 0)
            acc[0] = bflo(uself.x); acc[1] = bfhi(uself.x);
            acc[2] = bflo(uself.y); acc[3] = bfhi(uself.y);
            acc[4] = bflo(uself.z); acc[5] = bfhi(uself.z);
            acc[6] = bflo(uself.w); acc[7] = bfhi(uself.w);
        }
        #pragma unroll
        for (int k = 0; k < 8; ++k) {
            if (iv[k] < deg) {
                acc[0] += bflo(u[k].x); acc[1] += bfhi(u[k].x);
                acc[2] += bflo(u[k].y); acc[3] += bfhi(u[k].y);
                acc[4] += bflo(u[k].z); acc[5] += bfhi(u[k].z);
                acc[6] += bflo(u[k].w); acc[7] += bfhi(u[k].w);
            }
        }
    } else {
        // ---- rare path: some deg in (32,64], wave-uniform loop ----
        int e1 = (int)__builtin_nontemporal_load(&slots[((long long)node << 6) + 32 + l32]);
        if (g == 0) {
            uint4 uself = *(const uint4*)(xb + selfoff + c);
            acc[0] = bflo(uself.x); acc[1] = bfhi(uself.x);
            acc[2] = bflo(uself.y); acc[3] = bfhi(uself.y);
            acc[4] = bflo(uself.z); acc[5] = bfhi(uself.z);
            acc[6] = bflo(uself.w); acc[7] = bfhi(uself.w);
        }
        int degmax = (degA > degB) ? degA : degB;
        int trips = (degmax + 3) >> 2;       // wave-uniform, <= 16
        for (int k = 0; k < trips; ++k) {
            int i = k * 4 + g;               // 0..63; i<32 <=> k<8 (uniform)
            int s = (k < 8) ? __shfl(e0, i + h * 32)
                            : __shfl(e1, (i - 32) + h * 32);
            if (i < deg) {
                uint4 u = *(const uint4*)(xb + (long long)s * CH + c);
                acc[0] += bflo(u.x); acc[1] += bfhi(u.x);
                acc[2] += bflo(u.y); acc[3] += bfhi(u.y);
                acc[4] += bflo(u.z); acc[5] += bfhi(u.z);
                acc[6] += bflo(u.w); acc[7] += bfhi(u.w);
            }
        }
    }
    // reduce the 4 i-mod-4 partials within each 32-lane half
    #pragma unroll
    for (int k = 0; k < 8; ++k) {
        acc[k] += __shfl(acc[k], lane ^ 8);
        acc[k] += __shfl(acc[k], lane ^ 16);
    }
    if (g == 0) {
        uintx4 o;
        o.x = (unsigned int)f2bf(acc[0]) | ((unsigned int)f2bf(acc[1]) << 16);
        o.y = (unsigned int)f2bf(acc[2]) | ((unsigned int)f2bf(acc[3]) << 16);
        o.z = (unsigned int)f2bf(acc[4]) | ((unsigned int)f2bf(acc[5]) << 16);
        o.w = (unsigned int)f2bf(acc[6]) | ((unsigned int)f2bf(acc[7]) << 16);
        // NT: out is not re-read in this pass — don't let the store stream
        // write-allocate into L2 and evict xb. (ext_vector_type for builtin.)
        __builtin_nontemporal_store(o, (uintx4*)(out + selfoff + c));
    }
}

// ---------------- Fused MLP (GEMM1+GEMM2 [+GEMM3]) — R0 exact -------------
// MFMA 16x16x32 bf16. A-frag: row=lane&15, k=(lane>>4)*8+j.
// C/D: col=lane&15, row=(lane>>4)*4+reg.
template<bool FINAL>
__global__ __launch_bounds__(256, 4)
void mlp_kernel(const unsigned short* __restrict__ in,
                const unsigned short* __restrict__ wa, const float* __restrict__ ba,
                const unsigned short* __restrict__ wb, const float* __restrict__ bb,
                const unsigned short* __restrict__ wl, const float* __restrict__ bl,
                unsigned short* __restrict__ hout, float* __restrict__ fout) {
    __shared__ unsigned short Alds[64 * LDK];
    __shared__ unsigned short Hlds[64 * LDK];
    const int tid = threadIdx.x;
    const int wave = tid >> 6, lane = tid & 63, q = lane >> 4, ln = lane & 15;
    const int rowbase = blockIdx.x * 64;

    short8 wa_f[2][4], wb_f[2][4];
    #pragma unroll
    for (int t2 = 0; t2 < 2; ++t2) {
        int orow = (wave * 2 + t2) * 16 + ln;
        #pragma unroll
        for (int ks = 0; ks < 4; ++ks) {
            wa_f[t2][ks] = *(const short8*)(wa + orow * CH + q * 8 + ks * 32);
            wb_f[t2][ks] = *(const short8*)(wb + orow * CH + q * 8 + ks * 32);
        }
    }
    const float ba0 = ba[(wave * 2) * 16 + ln], ba1 = ba[(wave * 2 + 1) * 16 + ln];
    const float bb0 = bb[(wave * 2) * 16 + ln], bb1 = bb[(wave * 2 + 1) * 16 + ln];

    {
        const int group = tid >> 4, l16 = tid & 15;
        const int c = l16 * 8;
        #pragma unroll
        for (int i = 0; i < 4; ++i) {
            int row = group * 4 + i;
            *(uint4*)&Alds[row * LDK + c] =
                *(const uint4*)(in + (long long)(rowbase + row) * CH + c);
        }
    }
    __syncthreads();

    // GEMM1: H1 = relu(A @ Wa^T + ba) -> Hlds
    {
        floatx4 acc1[4][2];
        #pragma unroll
        for (int rg = 0; rg < 4; ++rg)
            #pragma unroll
            for (int t2 = 0; t2 < 2; ++t2) acc1[rg][t2] = (floatx4){0.f, 0.f, 0.f, 0.f};
        #pragma unroll
        for (int rg = 0; rg < 4; ++rg) {
            #pragma unroll
            for (int ks = 0; ks < 4; ++ks) {
                short8 af = *(const short8*)&Alds[(rg * 16 + ln) * LDK + q * 8 + ks * 32];
                #pragma unroll
                for (int t2 = 0; t2 < 2; ++t2)
                    acc1[rg][t2] = __builtin_amdgcn_mfma_f32_16x16x32_bf16(af, wa_f[t2][ks], acc1[rg][t2], 0, 0, 0);
            }
        }
        #pragma unroll
        for (int rg = 0; rg < 4; ++rg) {
            #pragma unroll
            for (int t2 = 0; t2 < 2; ++t2) {
                float bias = t2 ? ba1 : ba0;
                int col = (wave * 2 + t2) * 16 + ln;
                #pragma unroll
                for (int r = 0; r < 4; ++r) {
                    float v = fmaxf(acc1[rg][t2][r] + bias, 0.f);
                    Hlds[(rg * 16 + q * 4 + r) * LDK + col] = f2bf(v);
                }
            }
        }
    }
    __syncthreads();

    // GEMM2: H2 = relu(H1 @ Wb^T + bb) -> Alds (reuse)
    {
        floatx4 acc2[4][2];
        #pragma unroll
        for (int rg = 0; rg < 4; ++rg)
            #pragma unroll
            for (int t2 = 0; t2 < 2; ++t2) acc2[rg][t2] = (floatx4){0.f, 0.f, 0.f, 0.f};
        #pragma unroll
        for (int rg = 0; rg < 4; ++rg) {
            #pragma unroll
            for (int ks = 0; ks < 4; ++ks) {
                short8 hf = *(const short8*)&Hlds[(rg * 16 + ln) * LDK + q * 8 + ks * 32];
                #pragma unroll
                for (int t2 = 0; t2 < 2; ++t2)
                    acc2[rg][t2] = __builtin_amdgcn_mfma_f32_16x16x32_bf16(hf, wb_f[t2][ks], acc2[rg][t2], 0, 0, 0);
            }
        }
        #pragma unroll
        for (int rg = 0; rg < 4; ++rg) {
            #pragma unroll
            for (int t2 = 0; t2 < 2; ++t2) {
                float bias = t2 ? bb1 : bb0;
                int col = (wave * 2 + t2) * 16 + ln;
                #pragma unroll
                for (int r = 0; r < 4; ++r) {
                    float v = fmaxf(acc2[rg][t2][r] + bias, 0.f);
                    Alds[(rg * 16 + q * 4 + r) * LDK + col] = f2bf(v);
                }
            }
        }
    }
    __syncthreads();

    if (!FINAL) {
        const int group = tid >> 4, l16 = tid & 15;
        const int c = l16 * 8;
        #pragma unroll
        for (int i = 0; i < 4; ++i) {
            int row = group * 4 + i;
            *(uint4*)(hout + (long long)(rowbase + row) * CH + c) =
                *(const uint4*)&Alds[row * LDK + c];
        }
    } else {
        if (wave < 3) {
            short8 wl_f[4];
            #pragma unroll
            for (int ks = 0; ks < 4; ++ks)
                wl_f[ks] = *(const short8*)(wl + (wave * 16 + ln) * CH + q * 8 + ks * 32);
            int col = wave * 16 + ln;
            float blv = (col < NCLS) ? bl[col] : 0.f;
            floatx4 acc3[4];
            #pragma unroll
            for (int rg = 0; rg < 4; ++rg) acc3[rg] = (floatx4){0.f, 0.f, 0.f, 0.f};
            #pragma unroll
            for (int rg = 0; rg < 4; ++rg)
                #pragma unroll
                for (int ks = 0; ks < 4; ++ks) {
                    short8 hf = *(const short8*)&Alds[(rg * 16 + ln) * LDK + q * 8 + ks * 32];
                    acc3[rg] = __builtin_amdgcn_mfma_f32_16x16x32_bf16(hf, wl_f[ks], acc3[rg], 0, 0, 0);
                }
            if (col < NCLS) {
                #pragma unroll
                for (int rg = 0; rg < 4; ++rg)
                    #pragma unroll
                    for (int r = 0; r < 4; ++r)
                        fout[(long long)(rowbase + rg * 16 + q * 4 + r) * NCLS + col] = acc3[rg][r] + blv;
            }
        }
    }
}

extern "C" void kernel_launch(void* const* d_in, const int* in_sizes, int n_in,
                              void* d_out, int out_size, void* d_ws, size_t ws_size,
                              hipStream_t stream) {
    const float* x    = (const float*)d_in[0];
    const int*   ei   = (const int*)d_in[1];
    const float* w1a  = (const float*)d_in[2];
    const float* b1a  = (const float*)d_in[3];
    const float* w1b  = (const float*)d_in[4];
    const float* b1b  = (const float*)d_in[5];
    const float* w2a  = (const float*)d_in[6];
    const float* b2a  = (const float*)d_in[7];
    const float* w2b  = (const float*)d_in[8];
    const float* b2b  = (const float*)d_in[9];
    const float* wlin = (const float*)d_in[10];
    const float* blin = (const float*)d_in[11];
    const int E = in_sizes[1] / 2;
    const int* srcv = ei;
    const int* dstv = ei + E;

    const size_t NODEF = (size_t)NNODES * CH;                    // 5.12M elems
    unsigned short* wt   = (unsigned short*)d_ws;                // 143 KB, pad to 256 KB
    unsigned short* xb   = (unsigned short*)((char*)d_ws + 262144);
    unsigned short* bufA = xb + NODEF;                           // gathered input
    unsigned short* h1   = bufA + NODEF;
    int* cnt = (int*)(h1 + NODEF);                               // NNODES
    unsigned short* slots = (unsigned short*)(cnt + ((NNODES + 63) & ~63)); // NNODES*CAP u16

    prep_all<<<WT_BLKS + CVT_BLKS + CNTZ_BLKS, 256, 0, stream>>>(
        w1a, w1b, w2a, w2b, wlin, x, wt, xb, cnt);
    fill_slots<<<(E + 255) / 256, 256, 0, stream>>>(srcv, dstv, cnt, slots, E);

    const int M = CH * CH;

    // ---- layer 1 ----
    gather_split<<<2 * PBLKS, 256, 0, stream>>>(xb, cnt, slots, bufA);
    mlp_kernel<false><<<NNODES / 64, 256, 0, stream>>>(
        bufA, wt, b1a, wt + M, b1b, nullptr, nullptr, h1, nullptr);
    // ---- layer 2 + final linear ----
    gather_split<<<2 * PBLKS, 256, 0, stream>>>(h1, cnt, slots, bufA);
    mlp_kernel<true ><<<NNODES / 64, 256, 0, stream>>>(
        bufA, wt + 2 * M, b2a, wt + 3 * M, b2b, wt + 4 * M, blin,
        nullptr, (float*)d_out);
}

// Round 12
// 184.808 us; speedup vs baseline: 1.0184x; 1.0184x over previous
//
#include <hip/hip_runtime.h>
#include <hip/hip_bf16.h>

typedef __attribute__((ext_vector_type(8))) short short8;
typedef __attribute__((ext_vector_type(4))) float floatx4;
typedef __attribute__((ext_vector_type(4))) int intx4;

#define NNODES 40000
#define CH 128
#define NCLS 40
#define LDK 136   // 128 + 8 pad (bf16 elems) -> row stride 272 B, 16B-aligned
#define CAP 64    // padded-CSR slots per node (deg ~ Poisson(16); P(deg>64)~0)
#define PBLKS (NNODES / 8)                 // 5000 blocks per gather pass (8 nodes/blk)

#define WT_ELEMS (4 * CH * CH + 48 * CH)   // 71680
#define WT_BLKS  ((WT_ELEMS + 255) / 256)  // 280
#define CVT_N4   (NNODES * CH / 4)         // 1,280,000
#define CVT_BLKS ((CVT_N4 + 255) / 256)    // 5000
#define CNTZ_BLKS ((NNODES + 1023) / 1024) // zero 40000 ints, int4 x 256thr

// ============================ FINAL (R17 champion, 185.05 us) ==============
// Session conclusion — measured walls, every software axis bracketed:
//   gather x2: 164 MB random 128B-line reads each @ ~3.6 TB/s memory-system
//     random-access ceiling (~48 us each). Bracketed: ILP (R11/R13: fewer
//     loads-in-flight -> slower; VGPR-capped above 9), occupancy (R18:
//     already 8 waves/SIMD), working set (R16: half-footprint neutral),
//     cache pollution (R19: NT slots/cnt/out neutral), instruction count
//     (R16: halved, neutral), fusion (R15: barrier-phased loses TLP).
//   fill: 640K device-scope returning atomics @ ~16 G/s (~40 us).
//     Bracketed: R12 (64B padding neutral -> not line conflicts),
//     R17 (1 edge/thread, full TLP -> -3.6 us, saturated).
//   prep ~9 us (streaming BW), mlp x2 ~13 us each, + 6 launch gaps -> ~185.
// ===========================================================================

__device__ __forceinline__ unsigned short f2bf(float f) {
    union { float f; unsigned int u; } a; a.f = f;
    unsigned int r = a.u + 0x7FFFu + ((a.u >> 16) & 1u);
    return (unsigned short)(r >> 16);
}
__device__ __forceinline__ float bflo(unsigned int w) {
    union { unsigned int u; float f; } a; a.u = w << 16; return a.f;
}
__device__ __forceinline__ float bfhi(unsigned int w) {
    union { unsigned int u; float f; } a; a.u = w & 0xffff0000u; return a.f;
}

// R0 structure (proven best): separate prep_all and fill_slots.
__global__ __launch_bounds__(256) void prep_all(
        const float* __restrict__ w1a, const float* __restrict__ w1b,
        const float* __restrict__ w2a, const float* __restrict__ w2b,
        const float* __restrict__ wlin, const float* __restrict__ x,
        unsigned short* __restrict__ wt, unsigned short* __restrict__ xb,
        int* __restrict__ cnt) {
    int b = blockIdx.x;
    if (b < WT_BLKS) {
        int tid = b * 256 + threadIdx.x;
        const int M = CH * CH;
        if (tid < 4 * M) {
            int m = tid / M;
            int n = (tid % M) / CH;   // out channel
            int k = tid % CH;         // in channel
            const float* w = (m == 0) ? w1a : (m == 1) ? w1b : (m == 2) ? w2a : w2b;
            wt[tid] = f2bf(w[k * CH + n]);
        } else if (tid < WT_ELEMS) {
            int t = tid - 4 * M;
            int n = t / CH, k = t % CH;
            wt[tid] = (n < NCLS) ? f2bf(wlin[k * NCLS + n]) : (unsigned short)0;
        }
    } else if (b < WT_BLKS + CVT_BLKS) {
        int t = (b - WT_BLKS) * 256 + threadIdx.x;
        if (t < CVT_N4) {
            floatx4 v = __builtin_nontemporal_load((const floatx4*)(x + (long long)t * 4));
            union { unsigned short us[4]; uint2 u2; } pk;
            pk.us[0] = f2bf(v.x); pk.us[1] = f2bf(v.y);
            pk.us[2] = f2bf(v.z); pk.us[3] = f2bf(v.w);
            *(uint2*)(xb + (long long)t * 4) = pk.u2;
        }
    } else {
        int idx = (b - WT_BLKS - CVT_BLKS) * 1024 + threadIdx.x * 4;
        if (idx < NNODES) *(int4*)(cnt + idx) = make_int4(0, 0, 0, 0);
    }
}

// R17 fill (champion): 1 edge/thread, full-occupancy in-flight atomics.
__global__ __launch_bounds__(256) void fill_slots(const int* __restrict__ srcv,
                                                  const int* __restrict__ dstv,
                                                  int* __restrict__ cnt,
                                                  unsigned short* __restrict__ slots, int E) {
    int t = blockIdx.x * blockDim.x + threadIdx.x;
    if (t >= E) return;
    int s = srcv[t];
    int d = dstv[t];
    int pos = atomicAdd(&cnt[d], 1);
    if (pos < CAP) slots[((long long)d << 6) + pos] = (unsigned short)s;
}

// out[node] = xb[node] + sum_edges xb[src]   (bf16 in, fp32 acc, bf16 out)
// R16 gather: ILP-preserving channel-half split. Per pass p, blocks read
// only channels [64p, 64p+64). Wave handles 2 nodes (lanes 0-31 = A,
// 32-63 = B), 8 lanes per half-row, 8+1 x 16B loads in flight per lane.
__global__ __launch_bounds__(256) void gather_split(const unsigned short* __restrict__ xb,
                                                    const int* __restrict__ cnt,
                                                    const unsigned short* __restrict__ slots,
                                                    unsigned short* __restrict__ out) {
    int bid = blockIdx.x;
    const int pass = (bid >= PBLKS) ? 1 : 0;
    const int nb = bid - pass * PBLKS;
    const int wave = threadIdx.x >> 6;
    const int lane = threadIdx.x & 63;
    const int h = lane >> 5;                 // 0: node A half, 1: node B half
    const int l32 = lane & 31;
    const int g = l32 >> 3;                  // slot quarter 0..3 (i mod 4 partition)
    const int c = (lane & 7) * 8 + pass * 64;// channel base (bf16 elems)
    const int nA = nb * 8 + wave * 2;
    const int nB = nA + 1;
    const int node = h ? nB : nA;
    int degA = cnt[nA]; degA = (degA > CAP) ? CAP : degA;
    int degB = cnt[nB]; degB = (degB > CAP) ? CAP : degB;
    const int deg = h ? degB : degA;
    const long long selfoff = (long long)node * CH;

    // lanes 0-31 hold A's slots 0..31, lanes 32-63 hold B's slots 0..31
    int e0 = (int)slots[((long long)node << 6) + l32];

    float acc[8];
    #pragma unroll
    for (int k = 0; k < 8; ++k) acc[k] = 0.f;

    if (degA <= 32 && degB <= 32) {          // wave-uniform branch
        // ---- fast path: branchless, 8+1 loads in flight per lane ----
        uint4 u[8];
        int iv[8];
        #pragma unroll
        for (int k = 0; k < 8; ++k) {
            int i = k * 4 + g;               // 0..31
            int s = __shfl(e0, i + h * 32);  // full-exec shfl, own half
            iv[k] = i;
            long long off = (i < deg) ? (long long)s * CH : selfoff;
            u[k] = *(const uint4*)(xb + off + c);
        }
        uint4 uself = *(const uint4*)(xb + selfoff + c);
        if (g == 0) {   // self term (eps = 0)
            acc[0] = bflo(uself.x); acc[1] = bfhi(uself.x);
            acc[2] = bflo(uself.y); acc[3] = bfhi(uself.y);
            acc[4] = bflo(uself.z); acc[5] = bfhi(uself.z);
            acc[6] = bflo(uself.w); acc[7] = bfhi(uself.w);
        }
        #pragma unroll
        for (int k = 0; k < 8; ++k) {
            if (iv[k] < deg) {
                acc[0] += bflo(u[k].x); acc[1] += bfhi(u[k].x);
                acc[2] += bflo(u[k].y); acc[3] += bfhi(u[k].y);
                acc[4] += bflo(u[k].z); acc[5] += bfhi(u[k].z);
                acc[6] += bflo(u[k].w); acc[7] += bfhi(u[k].w);
            }
        }
    } else {
        // ---- rare path: some deg in (32,64], wave-uniform loop ----
        int e1 = (int)slots[((long long)node << 6) + 32 + l32];  // slots 32..63
        if (g == 0) {
            uint4 uself = *(const uint4*)(xb + selfoff + c);
            acc[0] = bflo(uself.x); acc[1] = bfhi(uself.x);
            acc[2] = bflo(uself.y); acc[3] = bfhi(uself.y);
            acc[4] = bflo(uself.z); acc[5] = bfhi(uself.z);
            acc[6] = bflo(uself.w); acc[7] = bfhi(uself.w);
        }
        int degmax = (degA > degB) ? degA : degB;
        int trips = (degmax + 3) >> 2;       // wave-uniform, <= 16
        for (int k = 0; k < trips; ++k) {
            int i = k * 4 + g;               // 0..63; i<32 <=> k<8 (uniform)
            int s = (k < 8) ? __shfl(e0, i + h * 32)
                            : __shfl(e1, (i - 32) + h * 32);
            if (i < deg) {
                uint4 u = *(const uint4*)(xb + (long long)s * CH + c);
                acc[0] += bflo(u.x); acc[1] += bfhi(u.x);
                acc[2] += bflo(u.y); acc[3] += bfhi(u.y);
                acc[4] += bflo(u.z); acc[5] += bfhi(u.z);
                acc[6] += bflo(u.w); acc[7] += bfhi(u.w);
            }
        }
    }
    // reduce the 4 i-mod-4 partials within each 32-lane half
    #pragma unroll
    for (int k = 0; k < 8; ++k) {
        acc[k] += __shfl(acc[k], lane ^ 8);
        acc[k] += __shfl(acc[k], lane ^ 16);
    }
    if (g == 0) {
        uint4 o;
        o.x = (unsigned int)f2bf(acc[0]) | ((unsigned int)f2bf(acc[1]) << 16);
        o.y = (unsigned int)f2bf(acc[2]) | ((unsigned int)f2bf(acc[3]) << 16);
        o.z = (unsigned int)f2bf(acc[4]) | ((unsigned int)f2bf(acc[5]) << 16);
        o.w = (unsigned int)f2bf(acc[6]) | ((unsigned int)f2bf(acc[7]) << 16);
        *(uint4*)(out + selfoff + c) = o;
    }
}

// ---------------- Fused MLP (GEMM1+GEMM2 [+GEMM3]) — R0 exact -------------
// MFMA 16x16x32 bf16. A-frag: row=lane&15, k=(lane>>4)*8+j.
// C/D: col=lane&15, row=(lane>>4)*4+reg.
template<bool FINAL>
__global__ __launch_bounds__(256, 4)
void mlp_kernel(const unsigned short* __restrict__ in,
                const unsigned short* __restrict__ wa, const float* __restrict__ ba,
                const unsigned short* __restrict__ wb, const float* __restrict__ bb,
                const unsigned short* __restrict__ wl, const float* __restrict__ bl,
                unsigned short* __restrict__ hout, float* __restrict__ fout) {
    __shared__ unsigned short Alds[64 * LDK];
    __shared__ unsigned short Hlds[64 * LDK];
    const int tid = threadIdx.x;
    const int wave = tid >> 6, lane = tid & 63, q = lane >> 4, ln = lane & 15;
    const int rowbase = blockIdx.x * 64;

    short8 wa_f[2][4], wb_f[2][4];
    #pragma unroll
    for (int t2 = 0; t2 < 2; ++t2) {
        int orow = (wave * 2 + t2) * 16 + ln;
        #pragma unroll
        for (int ks = 0; ks < 4; ++ks) {
            wa_f[t2][ks] = *(const short8*)(wa + orow * CH + q * 8 + ks * 32);
            wb_f[t2][ks] = *(const short8*)(wb + orow * CH + q * 8 + ks * 32);
        }
    }
    const float ba0 = ba[(wave * 2) * 16 + ln], ba1 = ba[(wave * 2 + 1) * 16 + ln];
    const float bb0 = bb[(wave * 2) * 16 + ln], bb1 = bb[(wave * 2 + 1) * 16 + ln];

    {
        const int group = tid >> 4, l16 = tid & 15;
        const int c = l16 * 8;
        #pragma unroll
        for (int i = 0; i < 4; ++i) {
            int row = group * 4 + i;
            *(uint4*)&Alds[row * LDK + c] =
                *(const uint4*)(in + (long long)(rowbase + row) * CH + c);
        }
    }
    __syncthreads();

    // GEMM1: H1 = relu(A @ Wa^T + ba) -> Hlds
    {
        floatx4 acc1[4][2];
        #pragma unroll
        for (int rg = 0; rg < 4; ++rg)
            #pragma unroll
            for (int t2 = 0; t2 < 2; ++t2) acc1[rg][t2] = (floatx4){0.f, 0.f, 0.f, 0.f};
        #pragma unroll
        for (int rg = 0; rg < 4; ++rg) {
            #pragma unroll
            for (int ks = 0; ks < 4; ++ks) {
                short8 af = *(const short8*)&Alds[(rg * 16 + ln) * LDK + q * 8 + ks * 32];
                #pragma unroll
                for (int t2 = 0; t2 < 2; ++t2)
                    acc1[rg][t2] = __builtin_amdgcn_mfma_f32_16x16x32_bf16(af, wa_f[t2][ks], acc1[rg][t2], 0, 0, 0);
            }
        }
        #pragma unroll
        for (int rg = 0; rg < 4; ++rg) {
            #pragma unroll
            for (int t2 = 0; t2 < 2; ++t2) {
                float bias = t2 ? ba1 : ba0;
                int col = (wave * 2 + t2) * 16 + ln;
                #pragma unroll
                for (int r = 0; r < 4; ++r) {
                    float v = fmaxf(acc1[rg][t2][r] + bias, 0.f);
                    Hlds[(rg * 16 + q * 4 + r) * LDK + col] = f2bf(v);
                }
            }
        }
    }
    __syncthreads();

    // GEMM2: H2 = relu(H1 @ Wb^T + bb) -> Alds (reuse)
    {
        floatx4 acc2[4][2];
        #pragma unroll
        for (int rg = 0; rg < 4; ++rg)
            #pragma unroll
            for (int t2 = 0; t2 < 2; ++t2) acc2[rg][t2] = (floatx4){0.f, 0.f, 0.f, 0.f};
        #pragma unroll
        for (int rg = 0; rg < 4; ++rg) {
            #pragma unroll
            for (int ks = 0; ks < 4; ++ks) {
                short8 hf = *(const short8*)&Hlds[(rg * 16 + ln) * LDK + q * 8 + ks * 32];
                #pragma unroll
                for (int t2 = 0; t2 < 2; ++t2)
                    acc2[rg][t2] = __builtin_amdgcn_mfma_f32_16x16x32_bf16(hf, wb_f[t2][ks], acc2[rg][t2], 0, 0, 0);
            }
        }
        #pragma unroll
        for (int rg = 0; rg < 4; ++rg) {
            #pragma unroll
            for (int t2 = 0; t2 < 2; ++t2) {
                float bias = t2 ? bb1 : bb0;
                int col = (wave * 2 + t2) * 16 + ln;
                #pragma unroll
                for (int r = 0; r < 4; ++r) {
                    float v = fmaxf(acc2[rg][t2][r] + bias, 0.f);
                    Alds[(rg * 16 + q * 4 + r) * LDK + col] = f2bf(v);
                }
            }
        }
    }
    __syncthreads();

    if (!FINAL) {
        const int group = tid >> 4, l16 = tid & 15;
        const int c = l16 * 8;
        #pragma unroll
        for (int i = 0; i < 4; ++i) {
            int row = group * 4 + i;
            *(uint4*)(hout + (long long)(rowbase + row) * CH + c) =
                *(const uint4*)&Alds[row * LDK + c];
        }
    } else {
        if (wave < 3) {
            short8 wl_f[4];
            #pragma unroll
            for (int ks = 0; ks < 4; ++ks)
                wl_f[ks] = *(const short8*)(wl + (wave * 16 + ln) * CH + q * 8 + ks * 32);
            int col = wave * 16 + ln;
            float blv = (col < NCLS) ? bl[col] : 0.f;
            floatx4 acc3[4];
            #pragma unroll
            for (int rg = 0; rg < 4; ++rg) acc3[rg] = (floatx4){0.f, 0.f, 0.f, 0.f};
            #pragma unroll
            for (int rg = 0; rg < 4; ++rg)
                #pragma unroll
                for (int ks = 0; ks < 4; ++ks) {
                    short8 hf = *(const short8*)&Alds[(rg * 16 + ln) * LDK + q * 8 + ks * 32];
                    acc3[rg] = __builtin_amdgcn_mfma_f32_16x16x32_bf16(hf, wl_f[ks], acc3[rg], 0, 0, 0);
                }
            if (col < NCLS) {
                #pragma unroll
                for (int rg = 0; rg < 4; ++rg)
                    #pragma unroll
                    for (int r = 0; r < 4; ++r)
                        fout[(long long)(rowbase + rg * 16 + q * 4 + r) * NCLS + col] = acc3[rg][r] + blv;
            }
        }
    }
}

extern "C" void kernel_launch(void* const* d_in, const int* in_sizes, int n_in,
                              void* d_out, int out_size, void* d_ws, size_t ws_size,
                              hipStream_t stream) {
    const float* x    = (const float*)d_in[0];
    const int*   ei   = (const int*)d_in[1];
    const float* w1a  = (const float*)d_in[2];
    const float* b1a  = (const float*)d_in[3];
    const float* w1b  = (const float*)d_in[4];
    const float* b1b  = (const float*)d_in[5];
    const float* w2a  = (const float*)d_in[6];
    const float* b2a  = (const float*)d_in[7];
    const float* w2b  = (const float*)d_in[8];
    const float* b2b  = (const float*)d_in[9];
    const float* wlin = (const float*)d_in[10];
    const float* blin = (const float*)d_in[11];
    const int E = in_sizes[1] / 2;
    const int* srcv = ei;
    const int* dstv = ei + E;

    const size_t NODEF = (size_t)NNODES * CH;                    // 5.12M elems
    unsigned short* wt   = (unsigned short*)d_ws;                // 143 KB, pad to 256 KB
    unsigned short* xb   = (unsigned short*)((char*)d_ws + 262144);
    unsigned short* bufA = xb + NODEF;                           // gathered input
    unsigned short* h1   = bufA + NODEF;
    int* cnt = (int*)(h1 + NODEF);                               // NNODES
    unsigned short* slots = (unsigned short*)(cnt + ((NNODES + 63) & ~63)); // NNODES*CAP u16

    prep_all<<<WT_BLKS + CVT_BLKS + CNTZ_BLKS, 256, 0, stream>>>(
        w1a, w1b, w2a, w2b, wlin, x, wt, xb, cnt);
    fill_slots<<<(E + 255) / 256, 256, 0, stream>>>(srcv, dstv, cnt, slots, E);

    const int M = CH * CH;

    // ---- layer 1 ----
    gather_split<<<2 * PBLKS, 256, 0, stream>>>(xb, cnt, slots, bufA);
    mlp_kernel<false><<<NNODES / 64, 256, 0, stream>>>(
        bufA, wt, b1a, wt + M, b1b, nullptr, nullptr, h1, nullptr);
    // ---- layer 2 + final linear ----
    gather_split<<<2 * PBLKS, 256, 0, stream>>>(h1, cnt, slots, bufA);
    mlp_kernel<true ><<<NNODES / 64, 256, 0, stream>>>(
        bufA, wt + 2 * M, b2a, wt + 3 * M, b2b, wt + 4 * M, blin,
        nullptr, (float*)d_out);
}